// Round 1
// baseline (93.628 us; speedup 1.0000x reference)
//
#include <hip/hip_runtime.h>

// Closed form of the reference QP:
//   z_unc = (x*x, 1);  z_act = (-x, 1)
//   feasible = (-x*x <= x)  -> z = feasible ? z_unc : z_act
// Output [B,2] row-major float32: interleaved (z1, 1.0) pairs.
//
// Pure streaming: 16B x-read + 32B out-write per thread (4 samples/thread).

__global__ __launch_bounds__(256) void qp_kernel(const float4* __restrict__ x4,
                                                 float4* __restrict__ out4,
                                                 int n4 /* = B/4 */) {
    int i = blockIdx.x * blockDim.x + threadIdx.x;
    if (i >= n4) return;

    float4 xv = x4[i];

    float x0 = xv.x, x1 = xv.y, x2 = xv.z, x3 = xv.w;
    float s0 = x0 * x0, s1 = x1 * x1, s2 = x2 * x2, s3 = x3 * x3;

    // feasible: -x^2 <= x  (matches jnp.where semantics incl. NaN -> false -> z_act)
    float z0 = (-s0 <= x0) ? s0 : -x0;
    float z1 = (-s1 <= x1) ? s1 : -x1;
    float z2 = (-s2 <= x2) ? s2 : -x2;
    float z3 = (-s3 <= x3) ? s3 : -x3;

    float4 o0 = make_float4(z0, 1.0f, z1, 1.0f);
    float4 o1 = make_float4(z2, 1.0f, z3, 1.0f);

    out4[2 * i + 0] = o0;
    out4[2 * i + 1] = o1;
}

extern "C" void kernel_launch(void* const* d_in, const int* in_sizes, int n_in,
                              void* d_out, int out_size, void* d_ws, size_t ws_size,
                              hipStream_t stream) {
    const float* x = (const float*)d_in[0];
    float* out = (float*)d_out;
    int n = in_sizes[0];          // B = 8388608 (divisible by 4)
    int n4 = n / 4;

    int block = 256;
    int grid = (n4 + block - 1) / block;   // 8192 blocks

    qp_kernel<<<grid, block, 0, stream>>>((const float4*)x, (float4*)out, n4);
}